// Round 12
// baseline (2396.756 us; speedup 1.0000x reference)
//
#include <hip/hip_runtime.h>
#include <math.h>

// LIF_13984413516471 — exact serial chain with precomputed first-spike
// continuation tables (branchless windows). B=128, S=128, H=128, K=8.
// Reference: one scalar accumulator per batch, sequential over (i,j,k);
// per substep: s += x; if (s > th[k]) s = 0.
// Outputs (B,S,K,H) fp32: outs | spikes. Bitwise-exact fp32 replay.
//
// Key identity: within an 8-t window (64 substeps), the reference chain
// equals the PURE prefix chain (no resets) bitwise up to and including the
// first spiking substep. After the first reset the state is 0, so the rest
// of the window is data-only: K[j] = exact STEP chain from 0 over substeps
// j+1..63 (precomputed). Window body = 64 pure adds + shadowed ballot
// detection + one branchless correction. No mid-window branches, no
// conservative bounds.

#define NB 128
#define NS 128
#define NH 128
#define NK 8
#define NT (NS * NH)            // 16384 t per batch
#define WL 8                    // window = 8 t (64 substeps)
#define NW2 (NT / WL)           // 2048 windows per batch
#define NG64 (NT / 64)          // 256 groups (64 t = 8 windows each)
#define NP64 (NW2 / 64)         // 32 store-groups (64 windows each)
#define OUTN ((size_t)NB * NS * NK * NH)

// ---- ws layouts (floats) ----
// K path:   s_ent [NB][NW2] | K [NB][NW2][64]
#define WS_SENT   0
#define WS_K      (NB * NW2)
#define WS_K_TOT  (NB * NW2 + (size_t)NB * NW2 * 64)
// M fallback path: s_ent | M [NB][NW2] | M64 [NB][NG64]
#define WS_M      (NB * NW2)
#define WS_M64    (2 * NB * NW2)
#define WS_M_TOT  (2 * NB * NW2 + NB * NG64)

__device__ __forceinline__ float rl(float v, int idx) {
    return __int_as_float(__builtin_amdgcn_readlane(__float_as_int(v), idx));
}

#define ADD8(xv) do { s += xv; s += xv; s += xv; s += xv; \
                      s += xv; s += xv; s += xv; s += xv; } while (0)
#define STEP8(xv) do { \
    s += xv; s = (s > th0) ? 0.0f : s; \
    s += xv; s = (s > th1) ? 0.0f : s; \
    s += xv; s = (s > th2) ? 0.0f : s; \
    s += xv; s = (s > th3) ? 0.0f : s; \
    s += xv; s = (s > th4) ? 0.0f : s; \
    s += xv; s = (s > th5) ? 0.0f : s; \
    s += xv; s = (s > th6) ? 0.0f : s; \
    s += xv; s = (s > th7) ? 0.0f : s; } while (0)

// ---------------- K path ----------------

// Continuation table: one wave per window; lane j computes the exact fp32
// STEP chain from s=0 over substeps j+1..63 of its window (data-only).
__global__ void __launch_bounds__(64)
lif_tab(const float* __restrict__ x, const float* __restrict__ th,
        float* __restrict__ K)
{
    const int wg = blockIdx.x;            // b*NW2 + w
    const int b = wg >> 11;               // / 2048
    const int w = wg & (NW2 - 1);
    const int lane = threadIdx.x;
    const float* xw = x + (size_t)b * NT + w * WL;

    float t[NK];
#pragma unroll
    for (int k = 0; k < NK; ++k) t[k] = th[k];

    float s = 0.0f;
    for (int ss = lane + 1; ss < 64; ++ss) {
        float xv = xw[ss >> 3];
        s += xv;
        s = (s > t[ss & 7]) ? 0.0f : s;
    }
    K[(size_t)wg * 64 + lane] = s;
}

// Chain: 1 batch per wave; all lanes run the scalar chain redundantly.
// Per window: 64 pure dependent adds (critical path); per substep a ballot
// bit accumulates into a 64-bit mask (v_cmp + SALU, issued in the add
// chain's shadow); tail corrects via K on first spike (branchless).
// x and K staged in lane registers (readlane broadcast), prefetched one
// group (64 t) ahead. Window-entry states collect per lane (cndmask) ->
// one coalesced store per 64 windows.
__global__ void __launch_bounds__(64, 1)
lif_chain_k(const float* __restrict__ x, const float* __restrict__ th,
            const float* __restrict__ K, float* __restrict__ s_ent)
{
    const int b = blockIdx.x;
    const int lane = threadIdx.x;
    const float* xb = x + (size_t)b * NT;
    const float* Kb = K + (size_t)b * NW2 * 64;
    float* seb = s_ent + (size_t)b * NW2;

    const float th0 = th[0], th1 = th[1], th2 = th[2], th3 = th[3];
    const float th4 = th[4], th5 = th[5], th6 = th[6], th7 = th[7];

    float s = 0.0f, keep = 0.0f;
    float cx = xb[lane];                   // x of group 0 (64 t)
    float kc[8], kn[8];
#pragma unroll
    for (int w = 0; w < 8; ++w) kc[w] = Kb[(size_t)w * 64 + lane];

    for (int p = 0; p < NP64; ++p) {
        for (int g8 = 0; g8 < 8; ++g8) {
            const int gg = p * 8 + g8;
            const int ggn = (gg + 1 < NG64) ? gg + 1 : gg;
            float nx = xb[(size_t)ggn * 64 + lane];
#pragma unroll
            for (int w = 0; w < 8; ++w)
                kn[w] = Kb[((size_t)ggn * 8 + w) * 64 + lane];

#pragma unroll
            for (int wi = 0; wi < 8; ++wi) {
                keep = (lane == g8 * 8 + wi) ? s : keep;
                unsigned long long acc = 0ull;
#pragma unroll
                for (int m = 0; m < 8; ++m) {
                    float xc = rl(cx, wi * 8 + m);
                    s += xc; acc |= __ballot(s > th0) & (1ull << (m * 8 + 0));
                    s += xc; acc |= __ballot(s > th1) & (1ull << (m * 8 + 1));
                    s += xc; acc |= __ballot(s > th2) & (1ull << (m * 8 + 2));
                    s += xc; acc |= __ballot(s > th3) & (1ull << (m * 8 + 3));
                    s += xc; acc |= __ballot(s > th4) & (1ull << (m * 8 + 4));
                    s += xc; acc |= __ballot(s > th5) & (1ull << (m * 8 + 5));
                    s += xc; acc |= __ballot(s > th6) & (1ull << (m * 8 + 6));
                    s += xc; acc |= __ballot(s > th7) & (1ull << (m * 8 + 7));
                }
                // first spike j = ffs-1; exact continuation K[j] (data-only)
                int ff = __ffsll((unsigned long long)acc);   // 0 or 1..64
                float kv = rl(kc[wi], ff ? ff - 1 : 0);
                s = ff ? kv : s;
            }
            cx = nx;
#pragma unroll
            for (int w = 0; w < 8; ++w) kc[w] = kn[w];
        }
        seb[(size_t)p * 64 + lane] = keep;   // coalesced, 1 store / 64 windows
    }
}

// ---------------- M fallback path (R10, 390 µs chain) ----------------

__global__ void lif_bounds(const float* __restrict__ x,
                           const float* __restrict__ th,
                           float* __restrict__ M, float* __restrict__ M64)
{
    int idx = blockIdx.x * 256 + threadIdx.x;   // flat over NB*NG64
    if (idx >= NB * NG64) return;
    int b = idx >> 8, gg = idx & (NG64 - 1);
    float t[NK];
#pragma unroll
    for (int k = 0; k < NK; ++k) t[k] = th[k];
    const float* xp = x + (size_t)b * NT + gg * 64;

    double pg = 0.0, gmax = -1e300;
#pragma unroll
    for (int w8 = 0; w8 < 8; ++w8) {
        double pw = 0.0, wmax = -1e300;
#pragma unroll
        for (int l = 0; l < 8; ++l) {
            double xv = (double)xp[w8 * 8 + l];
#pragma unroll
            for (int k = 0; k < NK; ++k) {
                pw += xv;
                wmax = fmax(wmax, pw - (double)t[k]);
            }
        }
        gmax = fmax(gmax, pg + wmax);
        pg += pw;
        M[(size_t)b * NW2 + gg * 8 + w8] =
            (float)(-wmax - 0.1 - 1e-6 * fabs(wmax));
    }
    M64[(size_t)b * NG64 + gg] = (float)(-gmax - 0.5 - 1e-6 * fabs(gmax));
}

__global__ void __launch_bounds__(64, 1)
lif_chain_m(const float* __restrict__ x, const float* __restrict__ th,
            const float* __restrict__ M, const float* __restrict__ M64,
            float* __restrict__ s_ent)
{
    const int b = blockIdx.x;
    const int lane = threadIdx.x;
    const float* xb   = x + (size_t)b * NT;
    const float* Mb   = M + (size_t)b * NW2;
    const float* M64b = M64 + (size_t)b * NG64;
    float* seb = s_ent + (size_t)b * NW2;

    const float th0 = th[0], th1 = th[1], th2 = th[2], th3 = th[3];
    const float th4 = th[4], th5 = th[5], th6 = th[6], th7 = th[7];

    float s = 0.0f, keep = 0.0f;
    float cx   = xb[lane];
    float cM   = Mb[lane];
    float cM64 = M64b[0];

    for (int p = 0; p < NP64; ++p) {
        float nM = Mb[(size_t)((p + 1 < NP64) ? p + 1 : p) * 64 + lane];
        for (int g8 = 0; g8 < 8; ++g8) {
            const int gg = p * 8 + g8;
            const int ggn = (gg + 1 < NG64) ? gg + 1 : gg;
            float nx   = xb[(size_t)ggn * 64 + lane];
            float nM64 = M64b[ggn];
            const int wbase = g8 * 8;

            int q64 = __builtin_amdgcn_readfirstlane((int)(s <= cM64));
            if (q64) {
                float xc = rl(cx, 0);
#pragma unroll
                for (int wi = 0; wi < 8; ++wi) {
                    keep = (lane == wbase + wi) ? s : keep;
#pragma unroll
                    for (int m = 0; m < 8; ++m) {
                        int ni = wi * 8 + m + 1; if (ni > 63) ni = 63;
                        float xn = rl(cx, ni);
                        ADD8(xc);
                        xc = xn;
                    }
                }
            } else {
#pragma unroll
                for (int wi = 0; wi < 8; ++wi) {
                    float Mc = rl(cM, wbase + wi);
                    keep = (lane == wbase + wi) ? s : keep;
                    float xc = rl(cx, wi * 8);
                    int q = __builtin_amdgcn_readfirstlane((int)(s <= Mc));
                    if (q) {
#pragma unroll
                        for (int m = 0; m < 8; ++m) {
                            int ni = wi * 8 + m + 1; if (ni > 63) ni = 63;
                            float xn = rl(cx, ni);
                            ADD8(xc);
                            xc = xn;
                        }
                    } else {
#pragma unroll
                        for (int m = 0; m < 8; ++m) {
                            int ni = wi * 8 + m + 1; if (ni > 63) ni = 63;
                            float xn = rl(cx, ni);
                            STEP8(xc);
                            xc = xn;
                        }
                    }
                }
            }
            cx = nx; cM64 = nM64;
        }
        seb[(size_t)p * 64 + lane] = keep;
        cM = nM;
    }
}

// ---------------- output pass (shared) ----------------

// Fully parallel, no serial section. block = (b, i), thread j.
// Lane j replays (j&7) t-steps from its window's entering state, then emits
// its own t's 8 outputs, coalesced per k-plane. Bitwise-exact replay.
__global__ void __launch_bounds__(128)
lif_out(const float* __restrict__ x, const float* __restrict__ th,
        const float* __restrict__ s_ent, float* __restrict__ out)
{
    const int j = threadIdx.x;             // 0..127
    const int i = blockIdx.x & (NS - 1);
    const int b = blockIdx.x >> 7;
    const int wl = j >> 3;                 // window within row (0..15)
    const int r  = j & 7;                  // position within window

    const float th0 = th[0], th1 = th[1], th2 = th[2], th3 = th[3];
    const float th4 = th[4], th5 = th[5], th6 = th[6], th7 = th[7];

    float s = s_ent[(size_t)b * NW2 + i * 16 + wl];
    const float* xrow = x + (size_t)b * NT + i * NH + (wl << 3);

    for (int m = 0; m < r; ++m) {          // replay to own t (<=7 steps)
        float xv = xrow[m];
        STEP8(xv);
    }
    float xv = xrow[r];

    float* o  = out + (((size_t)b * NS + i) * NK) * NH + j;
    float* sp = o + OUTN;
    float thr[NK];
#pragma unroll
    for (int k = 0; k < NK; ++k) thr[k] = th[k];
#pragma unroll
    for (int k = 0; k < NK; ++k) {
        s += xv;
        bool spike = s > thr[k];
        o[(size_t)k * NH]  = spike ? s : 0.0f;
        sp[(size_t)k * NH] = spike ? 1.0f : 0.0f;
        s = spike ? 0.0f : s;
    }
}

// Fallback if ws is tiny: single-pass, scattered writes (slow, correct).
__global__ void lif_mono(const float* __restrict__ x, const float* __restrict__ th,
                         float* __restrict__ out)
{
    int b = blockIdx.x * 64 + threadIdx.x;
    if (b >= NB) return;
    float thr[NK];
#pragma unroll
    for (int k = 0; k < NK; ++k) thr[k] = th[k];
    const float* xb = x + (size_t)b * NT;
    float s = 0.0f;
    for (int i = 0; i < NS; ++i)
        for (int j = 0; j < NH; ++j) {
            float xv = xb[i * NH + j];
#pragma unroll
            for (int k = 0; k < NK; ++k) {
                s += xv;
                bool spike = s > thr[k];
                size_t idx = (((size_t)b * NS + i) * NK + k) * NH + j;
                out[idx]        = spike ? s : 0.0f;
                out[OUTN + idx] = spike ? 1.0f : 0.0f;
                s = spike ? 0.0f : s;
            }
        }
}

extern "C" void kernel_launch(void* const* d_in, const int* in_sizes, int n_in,
                              void* d_out, int out_size, void* d_ws, size_t ws_size,
                              hipStream_t stream) {
    const float* x  = (const float*)d_in[0];   // (128,128,128) fp32
    const float* th = (const float*)d_in[1];   // (8,) fp32
    float* out = (float*)d_out;
    float* ws  = (float*)d_ws;

    if (ws_size >= WS_K_TOT * sizeof(float)) {
        float* s_ent = ws + WS_SENT;
        float* Kt    = ws + WS_K;
        lif_tab<<<dim3(NB * NW2), dim3(64), 0, stream>>>(x, th, Kt);
        lif_chain_k<<<dim3(NB), dim3(64), 0, stream>>>(x, th, Kt, s_ent);
        lif_out<<<dim3(NB * NS), dim3(128), 0, stream>>>(x, th, s_ent, out);
    } else if (ws_size >= (size_t)WS_M_TOT * sizeof(float)) {
        float* s_ent = ws + WS_SENT;
        float* Mbuf  = ws + WS_M;
        float* M64b  = ws + WS_M64;
        lif_bounds<<<dim3((NB * NG64 + 255) / 256), dim3(256), 0, stream>>>(x, th, Mbuf, M64b);
        lif_chain_m<<<dim3(NB), dim3(64), 0, stream>>>(x, th, Mbuf, M64b, s_ent);
        lif_out<<<dim3(NB * NS), dim3(128), 0, stream>>>(x, th, s_ent, out);
    } else {
        lif_mono<<<dim3(2), dim3(64), 0, stream>>>(x, th, out);
    }
}

// Round 13
// 780.683 us; speedup vs baseline: 3.0701x; 3.0701x over previous
//
#include <hip/hip_runtime.h>
#include <math.h>

// LIF_13984413516471 — exact serial chain as PURE-ADD chain + shadow exact
// first-spike detection (pairs capture + ballot) + precomputed data-only
// continuations K (asm-staged, latency-hidden). B=128, S=128, H=128, K=8.
// Reference: one scalar accumulator per batch, sequential over (i,j,k);
// per substep: s += x; if (s > th[k]) s = 0.
// Outputs (B,S,K,H) fp32: outs | spikes. Bitwise-exact fp32 replay.
//
// Identity: within an 8-t window (64 substeps), the reference chain equals
// the PURE add chain bitwise up to and including the first spiking substep.
// After that reset the state is 0 -> rest of window is data-only:
// K[j] = exact STEP chain from 0 over substeps j+1..63 (precomputed).
// Window = 64 dep adds (critical path) + shadowed detection + 1 readlane.

#define NB 128
#define NS 128
#define NH 128
#define NK 8
#define NT (NS * NH)            // 16384 t per batch
#define WL 8                    // window = 8 t (64 substeps)
#define NW2 (NT / WL)           // 2048 windows per batch
#define NG64 (NT / 64)          // 256 groups (64 t = 8 windows each)
#define NP64 (NW2 / 64)         // 32 store-groups (64 windows each)
#define OUTN ((size_t)NB * NS * NK * NH)

// ---- ws layouts (floats) ----
// K path: s_ent [NB][NW2] | K [NB][NW2][64]
#define WS_SENT   0
#define WS_K      (NB * NW2)
#define WS_K_TOT  ((size_t)NB * NW2 + (size_t)NB * NW2 * 64)
// M fallback path (R10): s_ent | M [NB][NW2] | M64 [NB][NG64]
#define WS_M      (NB * NW2)
#define WS_M64    (2 * NB * NW2)
#define WS_M_TOT  (2 * NB * NW2 + NB * NG64)

__device__ __forceinline__ float rl(float v, int idx) {
    return __int_as_float(__builtin_amdgcn_readlane(__float_as_int(v), idx));
}

#define ADD8(xv) do { s += xv; s += xv; s += xv; s += xv; \
                      s += xv; s += xv; s += xv; s += xv; } while (0)
#define STEP8(xv) do { \
    s += xv; s = (s > th0) ? 0.0f : s; \
    s += xv; s = (s > th1) ? 0.0f : s; \
    s += xv; s = (s > th2) ? 0.0f : s; \
    s += xv; s = (s > th3) ? 0.0f : s; \
    s += xv; s = (s > th4) ? 0.0f : s; \
    s += xv; s = (s > th5) ? 0.0f : s; \
    s += xv; s = (s > th6) ? 0.0f : s; \
    s += xv; s = (s > th7) ? 0.0f : s; } while (0)

// asm global load: forced VGPR dest, forced placement (volatile asm is a
// scheduling-region boundary — cannot sink to use).
#define GL(dst, addr, off) \
    asm volatile("global_load_dword %0, %1, off offset:" #off \
                 : "=v"(dst) : "v"(addr))

// ---------------- K table ----------------
// lane j of window wg: exact fp32 STEP chain from 0 over substeps j+1..63.
__global__ void __launch_bounds__(256)
lif_tab(const float* __restrict__ x, const float* __restrict__ th,
        float* __restrict__ K)
{
    const int wg = blockIdx.x * 4 + (threadIdx.x >> 6);   // b*NW2 + w
    const int lane = threadIdx.x & 63;
    const int b = wg >> 11;
    const int w = wg & (NW2 - 1);
    const float* xw = x + (size_t)b * NT + w * WL;

    float s = 0.0f;
#pragma unroll
    for (int t = 0; t < 8; ++t) {
        float xv = xw[t];
#pragma unroll
        for (int k = 0; k < 8; ++k) {
            int ss = t * 8 + k;
            if (ss > lane) {
                s += xv;
                s = (s > th[k]) ? 0.0f : s;
            }
        }
    }
    K[(size_t)wg * 64 + lane] = s;
}

// ---------------- chain (K path) ----------------
__global__ void __launch_bounds__(64, 1)
lif_chain_k(const float* __restrict__ x, const float* __restrict__ th,
            const float* __restrict__ K, float* __restrict__ s_ent)
{
    const int b = blockIdx.x;
    const int lane = threadIdx.x;
    const float* xb = x + (size_t)b * NT;
    const float* Kb = K + (size_t)b * NW2 * 64;
    float* seb = s_ent + (size_t)b * NW2;

    const float te = th[(2 * lane) & 7];        // even-substep threshold
    const float to = th[(2 * lane + 1) & 7];    // odd-substep threshold
    const int xb_byte = (lane >> 2) * 4;        // within-window t of this lane

    float s = 0.0f, keep = 0.0f;
    float pl = -3.0e38f;                        // lanes >=32 stay -inf forever

    // prologue: group 0 into kc0..kc7 / cx
    float kc0, kc1, kc2, kc3, kc4, kc5, kc6, kc7, cx;
    float kn0, kn1, kn2, kn3, kn4, kn5, kn6, kn7, nx;
    {
        uint64_t kb0 = (uint64_t)Kb + (uint64_t)lane * 4;
        uint64_t xb0 = (uint64_t)xb + (uint64_t)lane * 4;
        GL(kc0, kb0, 0);    GL(kc1, kb0, 256);  GL(kc2, kb0, 512);
        GL(kc3, kb0, 768);  GL(kc4, kb0, 1024); GL(kc5, kb0, 1280);
        GL(kc6, kb0, 1536); GL(kc7, kb0, 1792); GL(cx, xb0, 0);
        asm volatile("s_waitcnt vmcnt(0)" ::: "memory");
        __builtin_amdgcn_sched_barrier(0);
    }
    uint64_t kaddr = (uint64_t)Kb + (uint64_t)lane * 4 + 2048;  // group 1
    uint64_t xaddr = (uint64_t)xb + (uint64_t)lane * 4 + 256;

    for (int p = 0; p < NP64; ++p) {
        for (int g8 = 0; g8 < 8; ++g8) {
            const int gg = p * 8 + g8;
            // prefetch next group (clamped re-fetch at the end; never OOB)
            GL(kn0, kaddr, 0);    GL(kn1, kaddr, 256);  GL(kn2, kaddr, 512);
            GL(kn3, kaddr, 768);  GL(kn4, kaddr, 1024); GL(kn5, kaddr, 1280);
            GL(kn6, kaddr, 1536); GL(kn7, kaddr, 1792); GL(nx, xaddr, 0);
            if (gg + 2 < NG64) { kaddr += 2048; xaddr += 256; }

#pragma unroll
            for (int wi = 0; wi < 8; ++wi) {
                // per-lane x for odd-substep reconstruction (latency hidden)
                float xbl = __int_as_float(__builtin_amdgcn_ds_bpermute(
                    wi * 32 + xb_byte, __float_as_int(cx)));

                keep = (lane == g8 * 8 + wi) ? s : keep;   // window entry

                // 64 pure dependent adds; capture even-substep states:
                // lane L holds state after substep 2L (L = t*4 + k/2).
#pragma unroll
                for (int t = 0; t < 8; ++t) {
                    float xc = rl(cx, wi * 8 + t);
                    s += xc; pl = (lane == t * 4 + 0) ? s : pl;
                    s += xc;
                    s += xc; pl = (lane == t * 4 + 1) ? s : pl;
                    s += xc;
                    s += xc; pl = (lane == t * 4 + 2) ? s : pl;
                    s += xc;
                    s += xc; pl = (lane == t * 4 + 3) ? s : pl;
                    s += xc;
                }
                // exact first-spike detection (margin-free: pure chain ==
                // reference chain bitwise up to first spike; fp32 compare
                // sign is exact).
                float po = pl + xbl;                      // odd substep 2L+1
                unsigned long long be = __ballot(pl > te);
                unsigned long long bo = __ballot(po > to);
                int fe = __ffsll(be), fo = __ffsll(bo);
                int pe_ = fe ? 2 * (fe - 1) : 127;
                int po_ = fo ? 2 * (fo - 1) + 1 : 127;
                int tf = pe_ < po_ ? pe_ : po_;
                float kv;
                switch (wi) {   // static kc selection
                    case 0: kv = rl(kc0, tf & 63); break;
                    case 1: kv = rl(kc1, tf & 63); break;
                    case 2: kv = rl(kc2, tf & 63); break;
                    case 3: kv = rl(kc3, tf & 63); break;
                    case 4: kv = rl(kc4, tf & 63); break;
                    case 5: kv = rl(kc5, tf & 63); break;
                    case 6: kv = rl(kc6, tf & 63); break;
                    default: kv = rl(kc7, tf & 63); break;
                }
                s = (tf < 64) ? kv : s;   // spike -> data-only continuation
            }

            asm volatile("s_waitcnt vmcnt(0)" ::: "memory");
            __builtin_amdgcn_sched_barrier(0);
            kc0 = kn0; kc1 = kn1; kc2 = kn2; kc3 = kn3;
            kc4 = kn4; kc5 = kn5; kc6 = kn6; kc7 = kn7; cx = nx;
        }
        seb[(size_t)p * 64 + lane] = keep;   // coalesced, 1 store / 64 windows
    }
}

// ---------------- M fallback path (R10) ----------------
__global__ void lif_bounds(const float* __restrict__ x,
                           const float* __restrict__ th,
                           float* __restrict__ M, float* __restrict__ M64)
{
    int idx = blockIdx.x * 256 + threadIdx.x;
    if (idx >= NB * NG64) return;
    int b = idx >> 8, gg = idx & (NG64 - 1);
    float t[NK];
#pragma unroll
    for (int k = 0; k < NK; ++k) t[k] = th[k];
    const float* xp = x + (size_t)b * NT + gg * 64;
    double pg = 0.0, gmax = -1e300;
#pragma unroll
    for (int w8 = 0; w8 < 8; ++w8) {
        double pw = 0.0, wmax = -1e300;
#pragma unroll
        for (int l = 0; l < 8; ++l) {
            double xv = (double)xp[w8 * 8 + l];
#pragma unroll
            for (int k = 0; k < NK; ++k) {
                pw += xv;
                wmax = fmax(wmax, pw - (double)t[k]);
            }
        }
        gmax = fmax(gmax, pg + wmax);
        pg += pw;
        M[(size_t)b * NW2 + gg * 8 + w8] = (float)(-wmax - 0.1 - 1e-6 * fabs(wmax));
    }
    M64[(size_t)b * NG64 + gg] = (float)(-gmax - 0.5 - 1e-6 * fabs(gmax));
}

__global__ void __launch_bounds__(64, 1)
lif_chain_m(const float* __restrict__ x, const float* __restrict__ th,
            const float* __restrict__ M, const float* __restrict__ M64,
            float* __restrict__ s_ent)
{
    const int b = blockIdx.x;
    const int lane = threadIdx.x;
    const float* xb   = x + (size_t)b * NT;
    const float* Mb   = M + (size_t)b * NW2;
    const float* M64b = M64 + (size_t)b * NG64;
    float* seb = s_ent + (size_t)b * NW2;

    const float th0 = th[0], th1 = th[1], th2 = th[2], th3 = th[3];
    const float th4 = th[4], th5 = th[5], th6 = th[6], th7 = th[7];

    float s = 0.0f, keep = 0.0f;
    float cx   = xb[lane];
    float cM   = Mb[lane];
    float cM64 = M64b[0];

    for (int p = 0; p < NP64; ++p) {
        float nM = Mb[(size_t)((p + 1 < NP64) ? p + 1 : p) * 64 + lane];
        for (int g8 = 0; g8 < 8; ++g8) {
            const int gg = p * 8 + g8;
            const int ggn = (gg + 1 < NG64) ? gg + 1 : gg;
            float nx   = xb[(size_t)ggn * 64 + lane];
            float nM64 = M64b[ggn];
            const int wbase = g8 * 8;

            int q64 = __builtin_amdgcn_readfirstlane((int)(s <= cM64));
            if (q64) {
                float xc = rl(cx, 0);
#pragma unroll
                for (int wi = 0; wi < 8; ++wi) {
                    keep = (lane == wbase + wi) ? s : keep;
#pragma unroll
                    for (int m = 0; m < 8; ++m) {
                        int ni = wi * 8 + m + 1; if (ni > 63) ni = 63;
                        float xn = rl(cx, ni);
                        ADD8(xc);
                        xc = xn;
                    }
                }
            } else {
#pragma unroll
                for (int wi = 0; wi < 8; ++wi) {
                    float Mc = rl(cM, wbase + wi);
                    keep = (lane == wbase + wi) ? s : keep;
                    float xc = rl(cx, wi * 8);
                    int q = __builtin_amdgcn_readfirstlane((int)(s <= Mc));
                    if (q) {
#pragma unroll
                        for (int m = 0; m < 8; ++m) {
                            int ni = wi * 8 + m + 1; if (ni > 63) ni = 63;
                            float xn = rl(cx, ni);
                            ADD8(xc);
                            xc = xn;
                        }
                    } else {
#pragma unroll
                        for (int m = 0; m < 8; ++m) {
                            int ni = wi * 8 + m + 1; if (ni > 63) ni = 63;
                            float xn = rl(cx, ni);
                            STEP8(xc);
                            xc = xn;
                        }
                    }
                }
            }
            cx = nx; cM64 = nM64;
        }
        seb[(size_t)p * 64 + lane] = keep;
        cM = nM;
    }
}

// ---------------- output pass (shared) ----------------
__global__ void __launch_bounds__(128)
lif_out(const float* __restrict__ x, const float* __restrict__ th,
        const float* __restrict__ s_ent, float* __restrict__ out)
{
    const int j = threadIdx.x;
    const int i = blockIdx.x & (NS - 1);
    const int b = blockIdx.x >> 7;
    const int wl = j >> 3;
    const int r  = j & 7;

    const float th0 = th[0], th1 = th[1], th2 = th[2], th3 = th[3];
    const float th4 = th[4], th5 = th[5], th6 = th[6], th7 = th[7];

    float s = s_ent[(size_t)b * NW2 + i * 16 + wl];
    const float* xrow = x + (size_t)b * NT + i * NH + (wl << 3);

    for (int m = 0; m < r; ++m) {
        float xv = xrow[m];
        STEP8(xv);
    }
    float xv = xrow[r];

    float* o  = out + (((size_t)b * NS + i) * NK) * NH + j;
    float* sp = o + OUTN;
    float thr[NK];
#pragma unroll
    for (int k = 0; k < NK; ++k) thr[k] = th[k];
#pragma unroll
    for (int k = 0; k < NK; ++k) {
        s += xv;
        bool spike = s > thr[k];
        o[(size_t)k * NH]  = spike ? s : 0.0f;
        sp[(size_t)k * NH] = spike ? 1.0f : 0.0f;
        s = spike ? 0.0f : s;
    }
}

__global__ void lif_mono(const float* __restrict__ x, const float* __restrict__ th,
                         float* __restrict__ out)
{
    int b = blockIdx.x * 64 + threadIdx.x;
    if (b >= NB) return;
    float thr[NK];
#pragma unroll
    for (int k = 0; k < NK; ++k) thr[k] = th[k];
    const float* xb = x + (size_t)b * NT;
    float s = 0.0f;
    for (int i = 0; i < NS; ++i)
        for (int j = 0; j < NH; ++j) {
            float xv = xb[i * NH + j];
#pragma unroll
            for (int k = 0; k < NK; ++k) {
                s += xv;
                bool spike = s > thr[k];
                size_t idx = (((size_t)b * NS + i) * NK + k) * NH + j;
                out[idx]        = spike ? s : 0.0f;
                out[OUTN + idx] = spike ? 1.0f : 0.0f;
                s = spike ? 0.0f : s;
            }
        }
}

extern "C" void kernel_launch(void* const* d_in, const int* in_sizes, int n_in,
                              void* d_out, int out_size, void* d_ws, size_t ws_size,
                              hipStream_t stream) {
    const float* x  = (const float*)d_in[0];   // (128,128,128) fp32
    const float* th = (const float*)d_in[1];   // (8,) fp32
    float* out = (float*)d_out;
    float* ws  = (float*)d_ws;

    if (ws_size >= WS_K_TOT * sizeof(float)) {
        float* s_ent = ws + WS_SENT;
        float* Kt    = ws + WS_K;
        lif_tab<<<dim3(NB * NW2 / 4), dim3(256), 0, stream>>>(x, th, Kt);
        lif_chain_k<<<dim3(NB), dim3(64), 0, stream>>>(x, th, Kt, s_ent);
        lif_out<<<dim3(NB * NS), dim3(128), 0, stream>>>(x, th, s_ent, out);
    } else if (ws_size >= (size_t)WS_M_TOT * sizeof(float)) {
        float* s_ent = ws + WS_SENT;
        float* Mbuf  = ws + WS_M;
        float* M64b  = ws + WS_M64;
        lif_bounds<<<dim3((NB * NG64 + 255) / 256), dim3(256), 0, stream>>>(x, th, Mbuf, M64b);
        lif_chain_m<<<dim3(NB), dim3(64), 0, stream>>>(x, th, Mbuf, M64b, s_ent);
        lif_out<<<dim3(NB * NS), dim3(128), 0, stream>>>(x, th, s_ent, out);
    } else {
        lif_mono<<<dim3(2), dim3(64), 0, stream>>>(x, th, out);
    }
}

// Round 14
// 583.620 us; speedup vs baseline: 4.1067x; 1.3377x over previous
//
#include <hip/hip_runtime.h>
#include <math.h>

// LIF_13984413516471 — exact serial chain with per-window EXACT staircase:
// certified-quiet -> pure adds; certified-first-spike -> precomputed exact
// continuation K (skips the whole window!); uncertain (narrow margin band)
// -> exact STEP8 redo. B=128, S=128, H=128, K=8.
// Reference: one scalar accumulator per batch, sequential over (i,j,k);
// per substep: s += x; if (s > th[k]) s = 0.
// Outputs (B,S,K,H) fp32: outs | spikes. Bitwise-exact fp32 replay.
//
// Staircase: within a window (64 substeps), first-spike index tau(s) is a
// monotone step function of entering state s; breakpoints are the running-
// minimum records of m_j = th_k(j) - P_j (real arith). For s decisively
// above record i (s > r_i + M) and decisively below all earlier records
// (s < r_i' - M, i' < i), the fp32 chain provably spikes FIRST at j_i
// (margin M=0.08 >> 64-add fp32 drift <=0.0625 at |s|<=16384), resets to 0,
// and the window exit is the data-only exact fp32 chain K_i. For s below
// all records by M: provably spike-free -> pure adds are bitwise-exact.
// Otherwise: exact STEP8 (rare: |s - r| < M band, or >7 records).

#define NB 128
#define NS 128
#define NH 128
#define NK 8
#define NT (NS * NH)            // 16384 t per batch
#define WL 8                    // window = 8 t (64 substeps)
#define NW2 (NT / WL)           // 2048 windows per batch
#define NG64 (NT / 64)          // 256 groups (64 t = 8 windows each)
#define NP64 (NW2 / 64)         // 32 store-groups (64 windows each)
#define OUTN ((size_t)NB * NS * NK * NH)

// ---- ws layout (floats) ----
#define WS_SENT 0                               // s_ent [NB][NW2]
#define WS_PHI  (NB * NW2)                      // cHi   [NB][NG64][64]
#define WS_PLO  (WS_PHI + NB * NG64 * 64)       // cLo   [NB][NG64][64]
#define WS_PK   (WS_PLO + NB * NG64 * 64)       // K     [NB][NG64][64]
#define WS_G    (WS_PK  + NB * NG64 * 64)       // G     [NB][NG64]
#define WS_TOT  (WS_G + NB * NG64)              // ~26.3 MB

__device__ __forceinline__ float rl(float v, int idx) {
    return __int_as_float(__builtin_amdgcn_readlane(__float_as_int(v), idx));
}

#define ADD8(xv) do { s += xv; s += xv; s += xv; s += xv; \
                      s += xv; s += xv; s += xv; s += xv; } while (0)
#define STEP8(xv) do { \
    s += xv; s = (s > th0) ? 0.0f : s; \
    s += xv; s = (s > th1) ? 0.0f : s; \
    s += xv; s = (s > th2) ? 0.0f : s; \
    s += xv; s = (s > th3) ? 0.0f : s; \
    s += xv; s = (s > th4) ? 0.0f : s; \
    s += xv; s = (s > th5) ? 0.0f : s; \
    s += xv; s = (s > th6) ? 0.0f : s; \
    s += xv; s = (s > th7) ? 0.0f : s; } while (0)

// ---- staircase + continuation table: one thread per window ----
__global__ void __launch_bounds__(256)
lif_tab2(const float* __restrict__ x, const float* __restrict__ th,
         float* __restrict__ PHI, float* __restrict__ PLO,
         float* __restrict__ PK)
{
    int idx = blockIdx.x * 256 + threadIdx.x;   // b*NW2 + w
    if (idx >= NB * NW2) return;
    int b = idx >> 11, w = idx & (NW2 - 1);
    int gg = w >> 3, wi = w & 7;
    const float* xw = x + (size_t)b * NT + w * WL;
    float t[NK];
#pragma unroll
    for (int k = 0; k < NK; ++k) t[k] = th[k];

    // records of running min of m_j = th_k(j) - P_j (f64)
    double p = 0.0, rmin = 1e300;
    double rv[7]; int rj[7]; int nr = 0; int over = 0;
    for (int ss = 0; ss < 64; ++ss) {
        p += (double)xw[ss >> 3];
        double m = (double)t[ss & 7] - p;
        if (m < rmin) {
            rmin = m;
            if (nr < 7) { rv[nr] = m; rj[nr] = ss; ++nr; }
            else over = 1;
        }
    }
    const double MW = 0.08;
    float hi[8], lo[8], kk[8];
#pragma unroll
    for (int i = 0; i < 8; ++i) { hi[i] = 3e38f; lo[i] = 3e38f; kk[i] = 0.0f; }
    for (int i = 0; i < nr; ++i) {
        double g = MW + 1e-6 * fabs(rv[i]);
        hi[i] = (float)(rv[i] + g);
        lo[i] = (float)(rv[i] - g);
        float s2 = 0.0f;                    // exact fp32 chain from reset
        for (int ss = rj[i] + 1; ss < 64; ++ss) {
            s2 += xw[ss >> 3];
            s2 = (s2 > t[ss & 7]) ? 0.0f : s2;
        }
        kk[i] = s2;
    }
    if (over) {                             // catch-all: s above deepest
        double g = MW + 1e-6 * fabs(rmin);  // record but unresolved -> STEP8
        hi[7] = 3e38f;
        lo[7] = (float)(rmin - g);
        kk[7] = 0.0f;
    }
    size_t base = ((size_t)b * NG64 + gg) * 64 + wi * 8;
#pragma unroll
    for (int i = 0; i < 8; ++i) {
        PHI[base + i] = hi[i]; PLO[base + i] = lo[i]; PK[base + i] = kk[i];
    }
}

// group bound: one thread per 64-t group; G = min over 512 substeps of
// (th - prefix-from-group-start) - 0.6 (drift margin for 512 adds).
__global__ void __launch_bounds__(256)
lif_tabg(const float* __restrict__ x, const float* __restrict__ th,
         float* __restrict__ G)
{
    int idx = blockIdx.x * 256 + threadIdx.x;   // b*NG64 + gg
    if (idx >= NB * NG64) return;
    int b = idx >> 8, gg = idx & (NG64 - 1);
    const float* xg = x + (size_t)b * NT + gg * 64;
    float t[NK];
#pragma unroll
    for (int k = 0; k < NK; ++k) t[k] = th[k];
    double p = 0.0, minm = 1e300;
    for (int ti = 0; ti < 64; ++ti) {
        double xv = (double)xg[ti];
#pragma unroll
        for (int k = 0; k < NK; ++k) {
            p += xv;
            double m = (double)t[k] - p;
            minm = fmin(minm, m);
        }
    }
    G[idx] = (float)(minm - 0.6 - 1e-6 * fabs(minm));
}

// ---- chain: 1 batch per wave; staircase-certified windows ----
__global__ void __launch_bounds__(64, 1)
lif_chain_s(const float* __restrict__ x, const float* __restrict__ th,
            const float* __restrict__ PHI, const float* __restrict__ PLO,
            const float* __restrict__ PK, const float* __restrict__ Gb_,
            float* __restrict__ s_ent)
{
    const int b = blockIdx.x;
    const int lane = threadIdx.x;
    const float* xb   = x + (size_t)b * NT;
    const float* PHIb = PHI + (size_t)b * NG64 * 64;
    const float* PLOb = PLO + (size_t)b * NG64 * 64;
    const float* PKb  = PK  + (size_t)b * NG64 * 64;
    const float* Gb   = Gb_ + (size_t)b * NG64;
    float* seb = s_ent + (size_t)b * NW2;

    const float th0 = th[0], th1 = th[1], th2 = th[2], th3 = th[3];
    const float th4 = th[4], th5 = th[5], th6 = th[6], th7 = th[7];

    float s = 0.0f, keep = 0.0f;
    // group 0 staging (named scalars: R9/R10-proven prefetch pattern)
    float cHi = PHIb[lane], cLo = PLOb[lane], cK = PKb[lane];
    float cx  = xb[lane],   cG  = Gb[0];

    for (int p = 0; p < NP64; ++p) {
        for (int g8 = 0; g8 < 8; ++g8) {
            const int gg = p * 8 + g8;
            const int ggn = (gg + 1 < NG64) ? gg + 1 : gg;
            float nHi = PHIb[(size_t)ggn * 64 + lane];
            float nLo = PLOb[(size_t)ggn * 64 + lane];
            float nK  = PKb[(size_t)ggn * 64 + lane];
            float nx  = xb[(size_t)ggn * 64 + lane];
            float nG  = Gb[ggn];
            const int wbase = g8 * 8;

            int q64 = __builtin_amdgcn_readfirstlane((int)(s <= cG));
            if (q64) {
                // certified spike-free 64-t group: 512 bitwise-exact adds
#pragma unroll
                for (int wi = 0; wi < 8; ++wi) {
                    keep = (lane == wbase + wi) ? s : keep;
#pragma unroll
                    for (int m = 0; m < 8; ++m) {
                        float xc = rl(cx, wi * 8 + m);
                        ADD8(xc);
                    }
                }
            } else {
#pragma unroll
                for (int wi = 0; wi < 8; ++wi) {
                    keep = (lane == wbase + wi) ? s : keep;
                    // staircase classification (2 ballots, SGPR tail)
                    unsigned long long bHi = __ballot(s > cHi);
                    unsigned long long bLo = __ballot(s > cLo);
                    unsigned hi8 = (unsigned)(bHi >> (wi * 8)) & 0xffu;
                    unsigned lo8 = (unsigned)(bLo >> (wi * 8)) & 0xffu;
                    int ii = __ffs((int)hi8);            // 0 or 1..8
                    unsigned below = ii ? (lo8 & ((1u << (ii - 1)) - 1u))
                                        : lo8;
                    if (below == 0) {
                        if (ii) {
                            // certified first spike at record ii-1:
                            // exit = exact data-only continuation
                            s = rl(cK, wi * 8 + ii - 1);
                        } else {
                            // certified spike-free window: pure adds
#pragma unroll
                            for (int m = 0; m < 8; ++m) {
                                float xc = rl(cx, wi * 8 + m);
                                ADD8(xc);
                            }
                        }
                    } else {
                        // uncertain (margin band / >7 records): exact redo
#pragma unroll
                        for (int m = 0; m < 8; ++m) {
                            float xc = rl(cx, wi * 8 + m);
                            STEP8(xc);
                        }
                    }
                }
            }
            cHi = nHi; cLo = nLo; cK = nK; cx = nx; cG = nG;
        }
        seb[(size_t)p * 64 + lane] = keep;   // coalesced, 1 store/64 windows
    }
}

// ---- output pass: fully parallel, bitwise-exact replay ----
__global__ void __launch_bounds__(128)
lif_out(const float* __restrict__ x, const float* __restrict__ th,
        const float* __restrict__ s_ent, float* __restrict__ out)
{
    const int j = threadIdx.x;             // 0..127
    const int i = blockIdx.x & (NS - 1);
    const int b = blockIdx.x >> 7;
    const int wl = j >> 3;                 // window within row (0..15)
    const int r  = j & 7;                  // position within window

    const float th0 = th[0], th1 = th[1], th2 = th[2], th3 = th[3];
    const float th4 = th[4], th5 = th[5], th6 = th[6], th7 = th[7];

    float s = s_ent[(size_t)b * NW2 + i * 16 + wl];
    const float* xrow = x + (size_t)b * NT + i * NH + (wl << 3);

    for (int m = 0; m < r; ++m) {          // replay to own t (<=7 steps)
        float xv = xrow[m];
        STEP8(xv);
    }
    float xv = xrow[r];

    float* o  = out + (((size_t)b * NS + i) * NK) * NH + j;
    float* sp = o + OUTN;
    float thr[NK];
#pragma unroll
    for (int k = 0; k < NK; ++k) thr[k] = th[k];
#pragma unroll
    for (int k = 0; k < NK; ++k) {
        s += xv;
        bool spike = s > thr[k];
        o[(size_t)k * NH]  = spike ? s : 0.0f;
        sp[(size_t)k * NH] = spike ? 1.0f : 0.0f;
        s = spike ? 0.0f : s;
    }
}

// ---- fallback if ws is tiny ----
__global__ void lif_mono(const float* __restrict__ x, const float* __restrict__ th,
                         float* __restrict__ out)
{
    int b = blockIdx.x * 64 + threadIdx.x;
    if (b >= NB) return;
    float thr[NK];
#pragma unroll
    for (int k = 0; k < NK; ++k) thr[k] = th[k];
    const float* xb = x + (size_t)b * NT;
    float s = 0.0f;
    for (int i = 0; i < NS; ++i)
        for (int j = 0; j < NH; ++j) {
            float xv = xb[i * NH + j];
#pragma unroll
            for (int k = 0; k < NK; ++k) {
                s += xv;
                bool spike = s > thr[k];
                size_t idx = (((size_t)b * NS + i) * NK + k) * NH + j;
                out[idx]        = spike ? s : 0.0f;
                out[OUTN + idx] = spike ? 1.0f : 0.0f;
                s = spike ? 0.0f : s;
            }
        }
}

extern "C" void kernel_launch(void* const* d_in, const int* in_sizes, int n_in,
                              void* d_out, int out_size, void* d_ws, size_t ws_size,
                              hipStream_t stream) {
    const float* x  = (const float*)d_in[0];   // (128,128,128) fp32
    const float* th = (const float*)d_in[1];   // (8,) fp32
    float* out = (float*)d_out;
    float* ws  = (float*)d_ws;

    if (ws_size >= (size_t)WS_TOT * sizeof(float)) {
        float* s_ent = ws + WS_SENT;
        float* PHI   = ws + WS_PHI;
        float* PLO   = ws + WS_PLO;
        float* PK    = ws + WS_PK;
        float* G     = ws + WS_G;

        lif_tab2<<<dim3((NB * NW2 + 255) / 256), dim3(256), 0, stream>>>(x, th, PHI, PLO, PK);
        lif_tabg<<<dim3((NB * NG64 + 255) / 256), dim3(256), 0, stream>>>(x, th, G);
        lif_chain_s<<<dim3(NB), dim3(64), 0, stream>>>(x, th, PHI, PLO, PK, G, s_ent);
        lif_out<<<dim3(NB * NS), dim3(128), 0, stream>>>(x, th, s_ent, out);
    } else {
        lif_mono<<<dim3(2), dim3(64), 0, stream>>>(x, th, out);
    }
}

// Round 15
// 499.891 us; speedup vs baseline: 4.7946x; 1.1675x over previous
//
#include <hip/hip_runtime.h>
#include <math.h>

// LIF_13984413516471 — exact serial chain, three-tier certified windows:
//   tier 0: group-quiet (512 substeps) -> pure adds, 1 vote.
//   tier 1: window-quiet (64 substeps) -> pure adds, 1 readlane+vote (R10).
//   tier 2: staircase-certified first spike -> s = precomputed exact
//           continuation K (skips the window), ballot classification.
//   tier 3: uncertain (margin band / >7 records) -> exact STEP8 redo.
// Tables are scratch-free (named record slots, compile-time indices).
// B=128, S=128, H=128, K=8. Reference: one scalar accumulator per batch,
// sequential over (i,j,k); per substep: s += x; if (s > th[k]) s = 0.
// Outputs (B,S,K,H) fp32: outs | spikes. Bitwise-exact fp32 replay.
//
// Staircase (validated R14, absmax 0.0): within a window, first-spike index
// tau(s) is monotone in entering state s; breakpoints are running-min
// records of m_j = th_k(j) - P_j. s decisively above record i (> r_i + g)
// and decisively below all earlier records (< r_i' - g) -> fp32 chain
// provably first-spikes at j_i (g = 0.08 >> 64-add fp32 drift <= 0.031 at
// |s|<=16384), resets to 0, exit = data-only exact fp32 chain K_i.
// s <= rmin - g -> provably spike-free -> pure adds bitwise-exact.

#define NB 128
#define NS 128
#define NH 128
#define NK 8
#define NT (NS * NH)            // 16384 t per batch
#define WL 8                    // window = 8 t (64 substeps)
#define NW2 (NT / WL)           // 2048 windows per batch
#define NG64 (NT / 64)          // 256 groups (64 t = 8 windows each)
#define NP64 (NW2 / 64)         // 32 store-groups (64 windows each)
#define OUTN ((size_t)NB * NS * NK * NH)

// ---- ws layout (floats) ----
#define WS_SENT 0                               // s_ent [NB][NW2]
#define WS_PHI  (NB * NW2)                      // hi    [NB][NG64][64]
#define WS_PLO  (WS_PHI + NB * NG64 * 64)       // lo    [NB][NG64][64]
#define WS_PK   (WS_PLO + NB * NG64 * 64)       // K     [NB][NG64][64]
#define WS_G    (WS_PK  + NB * NG64 * 64)       // G     [NB][NG64]
#define WS_TOT  (WS_G + NB * NG64)              // ~26.3 MB

__device__ __forceinline__ float rl(float v, int idx) {
    return __int_as_float(__builtin_amdgcn_readlane(__float_as_int(v), idx));
}

#define ADD8(xv) do { s += xv; s += xv; s += xv; s += xv; \
                      s += xv; s += xv; s += xv; s += xv; } while (0)
#define STEP8(xv) do { \
    s += xv; s = (s > th0) ? 0.0f : s; \
    s += xv; s = (s > th1) ? 0.0f : s; \
    s += xv; s = (s > th2) ? 0.0f : s; \
    s += xv; s = (s > th3) ? 0.0f : s; \
    s += xv; s = (s > th4) ? 0.0f : s; \
    s += xv; s = (s > th5) ? 0.0f : s; \
    s += xv; s = (s > th6) ? 0.0f : s; \
    s += xv; s = (s > th7) ? 0.0f : s; } while (0)

// exact fp32 STEP chain from 0 over substeps j+1..63 (compile-time indices
// only: fully unrolled, predicated on ss > j -> registers, no scratch).
__device__ __forceinline__ float contK(const float* xr, const float* t, int j) {
    float s2 = 0.0f;
#pragma unroll
    for (int ti = 0; ti < 8; ++ti) {
        float xv = xr[ti];
#pragma unroll
        for (int k = 0; k < 8; ++k) {
            if (ti * 8 + k > j) {
                s2 += xv;
                s2 = (s2 > t[k]) ? 0.0f : s2;
            }
        }
    }
    return s2;
}

// ---- staircase tables: one thread per window, scratch-free ----
#define RECSLOT(i) \
    v##i = (rec && nr == i) ? m : v##i; \
    j##i = (rec && nr == i) ? ss : j##i;

__global__ void __launch_bounds__(256)
lif_tab2(const float* __restrict__ x, const float* __restrict__ th,
         float* __restrict__ PHI, float* __restrict__ PLO,
         float* __restrict__ PK)
{
    int idx = blockIdx.x * 256 + threadIdx.x;   // b*NW2 + w
    if (idx >= NB * NW2) return;
    int b = idx >> 11, w = idx & (NW2 - 1);
    int gg = w >> 3, wi = w & 7;
    const float* xw = x + (size_t)b * NT + w * WL;

    float t[NK];
#pragma unroll
    for (int k = 0; k < NK; ++k) t[k] = th[k];
    float xr[8];
#pragma unroll
    for (int ti = 0; ti < 8; ++ti) xr[ti] = xw[ti];

    // running-min records (first 7) of m_j = th_k(j) - P_j, f64, named slots
    double p = 0.0, rmin = 1e300;
    double v0 = 0, v1 = 0, v2 = 0, v3 = 0, v4 = 0, v5 = 0, v6 = 0;
    int j0 = 64, j1 = 64, j2 = 64, j3 = 64, j4 = 64, j5 = 64, j6 = 64;
    int nr = 0;
#pragma unroll
    for (int ti = 0; ti < 8; ++ti) {
        double xv = (double)xr[ti];
#pragma unroll
        for (int k = 0; k < 8; ++k) {
            p += xv;
            double m = (double)t[k] - p;
            bool rec = m < rmin;
            rmin = rec ? m : rmin;
            const int ss = ti * 8 + k;
            RECSLOT(0) RECSLOT(1) RECSLOT(2) RECSLOT(3)
            RECSLOT(4) RECSLOT(5) RECSLOT(6)
            nr = rec ? nr + 1 : nr;
        }
    }

    const double MW = 0.08;
#define MKSLOT(i) \
    float hi##i = (j##i < 64) ? (float)(v##i + MW + 1e-6 * fabs(v##i)) : 3e38f; \
    float lo##i = (j##i < 64) ? (float)(v##i - MW - 1e-6 * fabs(v##i)) : 3e38f; \
    float kk##i = (j##i < 64) ? contK(xr, t, j##i) : 0.0f;
    MKSLOT(0) MKSLOT(1) MKSLOT(2) MKSLOT(3) MKSLOT(4) MKSLOT(5) MKSLOT(6)
#undef MKSLOT
    // slot 7: catch-all. lo7 = true window-quiet bound (rmin incl. records
    // beyond slot 6); hi7 = +inf so slot 7 never certifies a skip.
    float lo7 = (float)(rmin - MW - 1e-6 * fabs(rmin));
    float hi7 = 3e38f, kk7 = 0.0f;

    size_t base = ((size_t)b * NG64 + gg) * 64 + (size_t)wi * 8;
    PHI[base + 0] = hi0; PHI[base + 1] = hi1; PHI[base + 2] = hi2;
    PHI[base + 3] = hi3; PHI[base + 4] = hi4; PHI[base + 5] = hi5;
    PHI[base + 6] = hi6; PHI[base + 7] = hi7;
    PLO[base + 0] = lo0; PLO[base + 1] = lo1; PLO[base + 2] = lo2;
    PLO[base + 3] = lo3; PLO[base + 4] = lo4; PLO[base + 5] = lo5;
    PLO[base + 6] = lo6; PLO[base + 7] = lo7;
    PK[base + 0] = kk0; PK[base + 1] = kk1; PK[base + 2] = kk2;
    PK[base + 3] = kk3; PK[base + 4] = kk4; PK[base + 5] = kk5;
    PK[base + 6] = kk6; PK[base + 7] = kk7;
}

// group bound: one thread per 64-t group; G = min over 512 substeps of
// (th - prefix-from-group-start) - 0.5 (drift margin for 512 adds, ~0.25).
__global__ void __launch_bounds__(256)
lif_tabg(const float* __restrict__ x, const float* __restrict__ th,
         float* __restrict__ G)
{
    int idx = blockIdx.x * 256 + threadIdx.x;   // b*NG64 + gg
    if (idx >= NB * NG64) return;
    int b = idx >> 8, gg = idx & (NG64 - 1);
    const float* xg = x + (size_t)b * NT + gg * 64;
    float t[NK];
#pragma unroll
    for (int k = 0; k < NK; ++k) t[k] = th[k];
    double p = 0.0, minm = 1e300;
    for (int ti = 0; ti < 64; ++ti) {
        double xv = (double)xg[ti];
#pragma unroll
        for (int k = 0; k < NK; ++k) {
            p += xv;
            minm = fmin(minm, (double)t[k] - p);
        }
    }
    G[idx] = (float)(minm - 0.5 - 1e-6 * fabs(minm));
}

// ---- chain: 1 batch per wave; three-tier certified windows ----
__global__ void __launch_bounds__(64, 1)
lif_chain_s(const float* __restrict__ x, const float* __restrict__ th,
            const float* __restrict__ PHI, const float* __restrict__ PLO,
            const float* __restrict__ PK, const float* __restrict__ Gb_,
            float* __restrict__ s_ent)
{
    const int b = blockIdx.x;
    const int lane = threadIdx.x;
    const float* xb = x + (size_t)b * NT;
    const float* Hb = PHI + (size_t)b * NG64 * 64;
    const float* Lb = PLO + (size_t)b * NG64 * 64;
    const float* Kb = PK  + (size_t)b * NG64 * 64;
    const float* Gb = Gb_ + (size_t)b * NG64;
    float* seb = s_ent + (size_t)b * NW2;

    const float th0 = th[0], th1 = th[1], th2 = th[2], th3 = th[3];
    const float th4 = th[4], th5 = th[5], th6 = th[6], th7 = th[7];

    float s = 0.0f, keep = 0.0f;
    float cH = Hb[lane], cL = Lb[lane], cK = Kb[lane];
    float cx = xb[lane], cG = Gb[0];

    for (int p = 0; p < NP64; ++p) {
        for (int g8 = 0; g8 < 8; ++g8) {
            const int gg = p * 8 + g8;
            const int ggn = (gg + 1 < NG64) ? gg + 1 : gg;
            float nH = Hb[(size_t)ggn * 64 + lane];
            float nL = Lb[(size_t)ggn * 64 + lane];
            float nK = Kb[(size_t)ggn * 64 + lane];
            float nx = xb[(size_t)ggn * 64 + lane];
            float nG = Gb[ggn];
            const int wbase = g8 * 8;

            int q64 = __builtin_amdgcn_readfirstlane((int)(s <= cG));
            if (q64) {
                // tier 0: certified spike-free 64-t group, 512 exact adds
#pragma unroll
                for (int wi = 0; wi < 8; ++wi) {
                    keep = (lane == wbase + wi) ? s : keep;
#pragma unroll
                    for (int m = 0; m < 8; ++m) {
                        float xc = rl(cx, wi * 8 + m);
                        ADD8(xc);
                    }
                }
            } else {
#pragma unroll
                for (int wi = 0; wi < 8; ++wi) {
                    keep = (lane == wbase + wi) ? s : keep;
                    // tier 1: window-quiet (catch-all lo in slot 7)
                    float wq = rl(cL, wi * 8 + 7);
                    int q = __builtin_amdgcn_readfirstlane((int)(s <= wq));
                    if (q) {
#pragma unroll
                        for (int m = 0; m < 8; ++m) {
                            float xc = rl(cx, wi * 8 + m);
                            ADD8(xc);
                        }
                    } else {
                        // tier 2/3: staircase classification
                        unsigned long long bHi = __ballot(s > cH);
                        unsigned long long bLo = __ballot(s > cL);
                        unsigned hi8 = (unsigned)(bHi >> (wi * 8)) & 0xffu;
                        unsigned lo8 = (unsigned)(bLo >> (wi * 8)) & 0xffu;
                        int ii = __ffs((int)hi8);          // 0 or 1..7
                        unsigned below = ii ? (lo8 & ((1u << (ii - 1)) - 1u))
                                            : lo8;
                        int skip = __builtin_amdgcn_readfirstlane(
                                       (int)(ii != 0 && below == 0));
                        if (skip) {
                            // certified first spike at record ii-1:
                            // exit = exact data-only continuation
                            s = rl(cK, wi * 8 + ii - 1);
                        } else {
                            // uncertain: exact STEP8 redo
#pragma unroll
                            for (int m = 0; m < 8; ++m) {
                                float xc = rl(cx, wi * 8 + m);
                                STEP8(xc);
                            }
                        }
                    }
                }
            }
            cH = nH; cL = nL; cK = nK; cx = nx; cG = nG;
        }
        seb[(size_t)p * 64 + lane] = keep;   // coalesced, 1 store/64 windows
    }
}

// ---- output pass: fully parallel, bitwise-exact replay ----
__global__ void __launch_bounds__(128)
lif_out(const float* __restrict__ x, const float* __restrict__ th,
        const float* __restrict__ s_ent, float* __restrict__ out)
{
    const int j = threadIdx.x;             // 0..127
    const int i = blockIdx.x & (NS - 1);
    const int b = blockIdx.x >> 7;
    const int wl = j >> 3;                 // window within row (0..15)
    const int r  = j & 7;                  // position within window

    const float th0 = th[0], th1 = th[1], th2 = th[2], th3 = th[3];
    const float th4 = th[4], th5 = th[5], th6 = th[6], th7 = th[7];

    float s = s_ent[(size_t)b * NW2 + i * 16 + wl];
    const float* xrow = x + (size_t)b * NT + i * NH + (wl << 3);

    for (int m = 0; m < r; ++m) {          // replay to own t (<=7 steps)
        float xv = xrow[m];
        STEP8(xv);
    }
    float xv = xrow[r];

    float* o  = out + (((size_t)b * NS + i) * NK) * NH + j;
    float* sp = o + OUTN;
    float thr[NK];
#pragma unroll
    for (int k = 0; k < NK; ++k) thr[k] = th[k];
#pragma unroll
    for (int k = 0; k < NK; ++k) {
        s += xv;
        bool spike = s > thr[k];
        o[(size_t)k * NH]  = spike ? s : 0.0f;
        sp[(size_t)k * NH] = spike ? 1.0f : 0.0f;
        s = spike ? 0.0f : s;
    }
}

// ---- fallback if ws is tiny ----
__global__ void lif_mono(const float* __restrict__ x, const float* __restrict__ th,
                         float* __restrict__ out)
{
    int b = blockIdx.x * 64 + threadIdx.x;
    if (b >= NB) return;
    float thr[NK];
#pragma unroll
    for (int k = 0; k < NK; ++k) thr[k] = th[k];
    const float* xb = x + (size_t)b * NT;
    float s = 0.0f;
    for (int i = 0; i < NS; ++i)
        for (int j = 0; j < NH; ++j) {
            float xv = xb[i * NH + j];
#pragma unroll
            for (int k = 0; k < NK; ++k) {
                s += xv;
                bool spike = s > thr[k];
                size_t idx = (((size_t)b * NS + i) * NK + k) * NH + j;
                out[idx]        = spike ? s : 0.0f;
                out[OUTN + idx] = spike ? 1.0f : 0.0f;
                s = spike ? 0.0f : s;
            }
        }
}

extern "C" void kernel_launch(void* const* d_in, const int* in_sizes, int n_in,
                              void* d_out, int out_size, void* d_ws, size_t ws_size,
                              hipStream_t stream) {
    const float* x  = (const float*)d_in[0];   // (128,128,128) fp32
    const float* th = (const float*)d_in[1];   // (8,) fp32
    float* out = (float*)d_out;
    float* ws  = (float*)d_ws;

    if (ws_size >= (size_t)WS_TOT * sizeof(float)) {
        float* s_ent = ws + WS_SENT;
        float* PHI   = ws + WS_PHI;
        float* PLO   = ws + WS_PLO;
        float* PK    = ws + WS_PK;
        float* G     = ws + WS_G;

        lif_tab2<<<dim3((NB * NW2 + 255) / 256), dim3(256), 0, stream>>>(x, th, PHI, PLO, PK);
        lif_tabg<<<dim3((NB * NG64 + 255) / 256), dim3(256), 0, stream>>>(x, th, G);
        lif_chain_s<<<dim3(NB), dim3(64), 0, stream>>>(x, th, PHI, PLO, PK, G, s_ent);
        lif_out<<<dim3(NB * NS), dim3(128), 0, stream>>>(x, th, s_ent, out);
    } else {
        lif_mono<<<dim3(2), dim3(64), 0, stream>>>(x, th, out);
    }
}